// Round 5
// baseline (12914.091 us; speedup 1.0000x reference)
//
#include <hip/hip_runtime.h>

// Problem constants
#define Tt    1024
#define INF   256
#define Hh    768
#define OUTF  128

// Grid: 48 L0 + 48 L1 + 2 LIN WGs, 1024 thr. Full batch per iteration.
// 2 barriers/iter, single-pass LDS staging, gate wave posts per-WG flag with
// a RELEASE store (wave-local drain), relay wave gang-polls producer lines.
// R5 fix vs R4: staging loads are back to SINGLE asm blocks (loads + vmcnt(0)
// together) -- the split issue/wait pattern let the register allocator touch
// load destinations before the drain (garbage -> NaN).
#define NWG_L0  48
#define NWG_L1  48
#define NWG_LIN 2
#define NWG     (NWG_L0 + NWG_L1 + NWG_LIN)   // 98
#define NTHR    1024
#define NIT     (Tt + 2)                      // 1026

typedef unsigned int       u32;
typedef unsigned short     u16;
typedef __attribute__((ext_vector_type(8))) short bf16x8;   // 8 bf16 = 4 VGPRs
typedef __attribute__((ext_vector_type(4))) float f32x4;    // MFMA C/D

// ws layout (bytes). prog[wg]: PRIVATE 128-B line, 1 writer, pollers read.
// h rings: [3 par][32 rows][768 j] bf16 per layer.
#define PROG_OFF 0
#define HPS      24576                        // u16 per [32][768] slab
#define HA_OFF   16384
#define HB_OFF   (HA_OFF + 3 * 49152)         // 163840
#define WS_BYTES (HB_OFF + 3 * 49152)         // 311296

// LDS (dynamic). act row strides (bytes): cols*2 + 16 pad (stride % 128 == 16).
#define AST0   2064      // L0: 1024 cols ([x 256 | hA 768])
#define AST1   3088      // L1: 1536 cols ([hA | hB])
#define AST2   1552      // LIN: 768 cols (hB)
#define ACT0_B (32 * AST0)                    // 66048
#define ACT1_B (32 * AST1)                    // 98816
#define ACT2_B (32 * AST2)                    // 49664
#define RSLAB  320       // red slab stride (dw): 16 cols x 20 dw
#define RCOL   20        // red col stride (dw) -> conflict-free f32x4 reduce
#define RED_B  (32 * RSLAB * 4)               // 40960
#define LDS_B  (ACT1_B + RED_B)               // 139776 (max over roles)

__device__ __forceinline__ float sigf(float v){ return 1.0f/(1.0f+__expf(-v)); }
__device__ __forceinline__ float tanhfast(float x){
    const float cx = fminf(fmaxf(x, -15.f), 15.f);
    const float e  = __expf(2.f * cx);
    return (e - 1.f) / (e + 1.f);
}
__device__ __forceinline__ u16 f2bf(float f){           // round-nearest-even
    u32 u = __float_as_uint(f);
    return (u16)((u + 0x7fffu + ((u>>16)&1u)) >> 16);
}
// LLC-coherent accesses for cross-WG data.
__device__ __forceinline__ void st32ws(u16* p, u32 v){
    __hip_atomic_store((u32*)p, v, __ATOMIC_RELAXED, __HIP_MEMORY_SCOPE_AGENT);
}
__device__ __forceinline__ u32 ldu32(const u32* p){
    return __hip_atomic_load(p, __ATOMIC_RELAXED, __HIP_MEMORY_SCOPE_AGENT);
}
__device__ __forceinline__ void stu32(u32* p, u32 v){
    __hip_atomic_store(p, v, __ATOMIC_RELAXED, __HIP_MEMORY_SCOPE_AGENT);
}
// Batched cache-bypassing loads: ALL loads + single vmcnt(0) drain inside ONE
// asm block, so outputs are never visible to regalloc before the drain.
__device__ __forceinline__ void ld16x3(const u16* p0, const u16* p1, const u16* p2,
                                       f32x4& r0, f32x4& r1, f32x4& r2){
    asm volatile(
        "global_load_dwordx4 %0, %3, off sc0 sc1\n\t"
        "global_load_dwordx4 %1, %4, off sc0 sc1\n\t"
        "global_load_dwordx4 %2, %5, off sc0 sc1\n\t"
        "s_waitcnt vmcnt(0)"
        : "=&v"(r0), "=&v"(r1), "=&v"(r2)
        : "v"(p0), "v"(p1), "v"(p2)
        : "memory");
}
__device__ __forceinline__ void ld16x5(const u16* p0, const u16* p1, const u16* p2,
                                       const u16* p3, const u16* p4,
                                       f32x4& r0, f32x4& r1, f32x4& r2,
                                       f32x4& r3, f32x4& r4){
    asm volatile(
        "global_load_dwordx4 %0, %5, off sc0 sc1\n\t"
        "global_load_dwordx4 %1, %6, off sc0 sc1\n\t"
        "global_load_dwordx4 %2, %7, off sc0 sc1\n\t"
        "global_load_dwordx4 %3, %8, off sc0 sc1\n\t"
        "global_load_dwordx4 %4, %9, off sc0 sc1\n\t"
        "s_waitcnt vmcnt(0)"
        : "=&v"(r0), "=&v"(r1), "=&v"(r2), "=&v"(r3), "=&v"(r4)
        : "v"(p0), "v"(p1), "v"(p2), "v"(p3), "v"(p4)
        : "memory");
}
__device__ __forceinline__ void ld16x7(const u16* p0, const u16* p1, const u16* p2,
                                       const u16* p3, const u16* p4, const u16* p5,
                                       const u16* p6,
                                       f32x4& r0, f32x4& r1, f32x4& r2, f32x4& r3,
                                       f32x4& r4, f32x4& r5, f32x4& r6){
    asm volatile(
        "global_load_dwordx4 %0, %7, off sc0 sc1\n\t"
        "global_load_dwordx4 %1, %8, off sc0 sc1\n\t"
        "global_load_dwordx4 %2, %9, off sc0 sc1\n\t"
        "global_load_dwordx4 %3, %10, off sc0 sc1\n\t"
        "global_load_dwordx4 %4, %11, off sc0 sc1\n\t"
        "global_load_dwordx4 %5, %12, off sc0 sc1\n\t"
        "global_load_dwordx4 %6, %13, off sc0 sc1\n\t"
        "s_waitcnt vmcnt(0)"
        : "=&v"(r0), "=&v"(r1), "=&v"(r2), "=&v"(r3),
          "=&v"(r4), "=&v"(r5), "=&v"(r6)
        : "v"(p0), "v"(p1), "v"(p2), "v"(p3), "v"(p4), "v"(p5), "v"(p6)
        : "memory");
}
__device__ __forceinline__ void waitvm(){
    asm volatile("s_waitcnt vmcnt(0)" ::: "memory");
}

__global__ void prologue(char* ws){
    int i = blockIdx.x * 256 + threadIdx.x;
    if (i < WS_BYTES / 4)
        __hip_atomic_store(((u32*)ws) + i, 0u, __ATOMIC_RELAXED, __HIP_MEMORY_SCOPE_AGENT);
}

__device__ __forceinline__ bf16x8 load8w(const float* p){
    float4 v0 = *(const float4*)(p);
    float4 v1 = *(const float4*)(p + 4);
    bf16x8 r;
    r[0]=(short)f2bf(v0.x); r[1]=(short)f2bf(v0.y); r[2]=(short)f2bf(v0.z); r[3]=(short)f2bf(v0.w);
    r[4]=(short)f2bf(v1.x); r[5]=(short)f2bf(v1.y); r[6]=(short)f2bf(v1.z); r[7]=(short)f2bf(v1.w);
    return r;
}

__global__ __launch_bounds__(NTHR) void lstm_persist(
    const float* __restrict__ x,
    const float* __restrict__ Wih0, const float* __restrict__ Whh0,
    const float* __restrict__ bih0, const float* __restrict__ bhh0,
    const float* __restrict__ Wih1, const float* __restrict__ Whh1,
    const float* __restrict__ bih1, const float* __restrict__ bhh1,
    const float* __restrict__ Wlin, const float* __restrict__ blin,
    float* __restrict__ out, char* ws)
{
    u32* prog = (u32*)(ws + PROG_OFF);
    u16* hA   = (u16*)(ws + HA_OFF);
    u16* hB   = (u16*)(ws + HB_OFF);

    const int wg  = blockIdx.x;
    const int tid = threadIdx.x;

    extern __shared__ __align__(16) char smem[];
    __shared__ u32 rdy;

    const int lane = tid & 63, w = tid >> 6;
    const int quad = lane >> 4, nl = lane & 15;
    const int nt = w >> 2, ks = w & 3;          // gate/out tile, K-slice

    const int role  = (wg < NWG_L0) ? 0 : ((wg < NWG_L0 + NWG_L1) ? 1 : 2);
    const int jbase = (role == 0) ? wg * 16 : ((role == 1) ? (wg - NWG_L0) * 16 : 0);
    const int obase = (role == 2) ? (wg - NWG_L0 - NWG_L1) * 64 : 0;

    char*  actb = smem;
    float* red  = (float*)(smem + ((role == 0) ? ACT0_B : (role == 1) ? ACT1_B : ACT2_B));

    // ---- register-resident bf16 weights (B-frags): n = lane&15, k = quad*8+j ----
    bf16x8 bfr[12];
    if (role == 0) {
        const int grow = nt * Hh + jbase + nl;
        #pragma unroll
        for (int fi = 0; fi < 8; ++fi) {
            const int ka = ks * 256 + fi * 32 + quad * 8;      // K: [x(256); hA(768)]
            const float* p = (ka < 256) ? (Wih0 + (size_t)grow * 256 + ka)
                                        : (Whh0 + (size_t)grow * 768 + (ka - 256));
            bfr[fi] = load8w(p);
        }
    } else if (role == 1) {
        const int grow = nt * Hh + jbase + nl;
        #pragma unroll
        for (int fi = 0; fi < 12; ++fi) {
            const int ka = ks * 384 + fi * 32 + quad * 8;      // K: [hA; hB]
            const float* p = (ka < 768) ? (Wih1 + (size_t)grow * 768 + ka)
                                        : (Whh1 + (size_t)grow * 768 + (ka - 768));
            bfr[fi] = load8w(p);
        }
    } else {
        const int row = obase + nt * 16 + nl;
        #pragma unroll
        for (int fi = 0; fi < 6; ++fi) {
            const int ka = ks * 192 + fi * 32 + quad * 8;
            bfr[fi] = load8w(Wlin + (size_t)row * 768 + ka);
        }
    }

    // ---- gate-wave (w15) state: thread (jp = lane>>3, rg = lane&7) ----
    // owns j-pair {jbase+2jp, +1} x rows 4rg..4rg+3.
    float ba[4] = {0,0,0,0}, bb[4] = {0,0,0,0};
    float ca[4] = {0,0,0,0}, cb[4] = {0,0,0,0};
    if (role < 2 && w == 15) {
        const float* bi = (role == 0) ? bih0 : bih1;
        const float* bh = (role == 0) ? bhh0 : bhh1;
        const int jg0 = jbase + 2 * (lane >> 3), jg1 = jg0 + 1;
        #pragma unroll
        for (int g = 0; g < 4; ++g) {
            ba[g] = bi[g * 768 + jg0] + bh[g * 768 + jg0];
            bb[g] = bi[g * 768 + jg1] + bh[g * 768 + jg1];
        }
    }
    float bl0 = 0.f, bl1 = 0.f;
    if (role == 2) {
        bl0 = blin[obase + (tid & 31)];
        bl1 = blin[obase + 32 + (tid & 31)];
    }

    if (tid == 0) __hip_atomic_store(&rdy, 0u, __ATOMIC_RELAXED, __HIP_MEMORY_SCOPE_WORKGROUP);
    __syncthreads();

    for (int s = 0; s < NIT; ++s) {
        const int par_wA = s % 3;              // hA(s)
        const int par_rA = (s + 2) % 3;        // hA(s-1)
        const int par_wB = (s + 2) % 3;        // hB(s-1)
        const int par_rB = (s + 1) % 3;        // hB(s-2)
        const bool active = (role == 0) ? (s < Tt)
                          : (role == 1) ? (s >= 1 && s <= Tt)
                          :               (s >= 2);
        if (active) {
            // ---- dependency wait: wave 14 gang-polls (<=2 lines/lane), LDS relay ----
            if (w == 14) {
                int ia = -1, ib = -1; u32 ta = 0, tb = 0;
                if (role == 0) {
                    if (lane < 48) {
                        ia = lane; ta = (u32)s;                          // hA(s-1): L0 fin s-1
                        if (s >= 3) { ib = 48 + lane; tb = (u32)(s-1); } // WAR: L1 fin s-2
                    }
                } else if (role == 1) {
                    if (lane < 48) {
                        ia = lane; ta = (u32)s;                          // hA(s-1): L0 fin s-1
                        ib = 48 + lane;
                        tb = (s >= 2) ? (u32)s : 0u;                     // hB(s-2): L1 fin s-1
                    } else if (lane < 50) {
                        ib = 48 + lane;                                  // LIN lines 96/97
                        tb = (s >= 4) ? (u32)(s-1) : 0u;                 // WAR: LIN fin s-2
                    }
                } else {
                    if (lane < 48) { ia = 48 + lane; ta = (u32)s; }      // hB(s-2): L1 fin s-1
                }
                int guard = 0;
                while (guard < (1 << 24)) {
                    const bool o1 = (ia < 0) || (ldu32(prog + ia * 32) >= ta);
                    const bool o2 = (ib < 0) || (ldu32(prog + ib * 32) >= tb);
                    if (__ballot(o1 && o2) == ~0ull) break;
                    __builtin_amdgcn_s_sleep(1); ++guard;
                }
                if (lane == 0)
                    __hip_atomic_store(&rdy, (u32)(s + 1), __ATOMIC_RELAXED, __HIP_MEMORY_SCOPE_WORKGROUP);
            } else {
                int guard = 0;
                while (guard < (1 << 24) &&
                       __hip_atomic_load(&rdy, __ATOMIC_RELAXED, __HIP_MEMORY_SCOPE_WORKGROUP) < (u32)(s + 1)) {
                    __builtin_amdgcn_s_sleep(1); ++guard;
                }
            }

            // ---- single-pass staging into act (waves 0..14; LIN: all 16) ----
            if (role == 0) {
                if (tid < 960) {
                    const u16* hsrc = hA + (size_t)par_rA * HPS;
                    int Gv[5]; u32 la[5]; bool vx[5], vh[5]; const u16* pp[5];
                    #pragma unroll
                    for (int u = 0; u < 5; ++u) {
                        Gv[u] = (u < 4) ? (u * 960 + tid) : (3840 + tid);
                        const bool val = (u < 4) || (tid < 256);
                        const int row = Gv[u] >> 7, c = Gv[u] & 127;
                        la[u] = (u32)(row * AST0 + c * 16);
                        vx[u] = val && (c < 32);
                        vh[u] = val && (c >= 32);
                        pp[u] = vh[u] ? (hsrc + (size_t)row * 768 + (size_t)(c - 32) * 8)
                                      : hsrc;   // clamp (discarded)
                    }
                    // x path first (plain compiler-tracked loads)
                    #pragma unroll
                    for (int u = 0; u < 5; ++u) if (vx[u]) {
                        const int row = Gv[u] >> 7, c = Gv[u] & 127;
                        const float* xs = x + ((size_t)row * Tt + s) * INF + c * 8;
                        const float4 v0 = ((const float4*)xs)[0];
                        const float4 v1 = ((const float4*)xs)[1];
                        uint4 a;
                        a.x = (u32)f2bf(v0.x) | ((u32)f2bf(v0.y) << 16);
                        a.y = (u32)f2bf(v0.z) | ((u32)f2bf(v0.w) << 16);
                        a.z = (u32)f2bf(v1.x) | ((u32)f2bf(v1.y) << 16);
                        a.w = (u32)f2bf(v1.z) | ((u32)f2bf(v1.w) << 16);
                        *(uint4*)(actb + la[u]) = a;
                    }
                    f32x4 h0, h1, h2, h3, h4;
                    ld16x5(pp[0], pp[1], pp[2], pp[3], pp[4], h0, h1, h2, h3, h4);
                    if (vh[0]) *(f32x4*)(actb + la[0]) = h0;
                    if (vh[1]) *(f32x4*)(actb + la[1]) = h1;
                    if (vh[2]) *(f32x4*)(actb + la[2]) = h2;
                    if (vh[3]) *(f32x4*)(actb + la[3]) = h3;
                    if (vh[4]) *(f32x4*)(actb + la[4]) = h4;
                }
            } else if (role == 1) {
                if (tid < 960) {
                    const u16* pA = hA + (size_t)par_rA * HPS;
                    const u16* pB = hB + (size_t)par_rB * HPS;
                    u32 la[7]; const u16* pp[7]; bool v6 = (tid < 384);
                    #pragma unroll
                    for (int u = 0; u < 7; ++u) {
                        const int G = (u < 6) ? (u * 960 + tid) : (5760 + tid);
                        const bool val = (u < 6) || v6;
                        const int row = G / 192, c = G - row * 192;
                        la[u] = (u32)(row * AST1 + c * 16);
                        pp[u] = !val ? pA
                              : (c < 96) ? (pA + (size_t)row * 768 + (size_t)c * 8)
                                         : (pB + (size_t)row * 768 + (size_t)(c - 96) * 8);
                    }
                    f32x4 h0, h1, h2, h3, h4, h5, h6;
                    ld16x7(pp[0], pp[1], pp[2], pp[3], pp[4], pp[5], pp[6],
                           h0, h1, h2, h3, h4, h5, h6);
                    *(f32x4*)(actb + la[0]) = h0;
                    *(f32x4*)(actb + la[1]) = h1;
                    *(f32x4*)(actb + la[2]) = h2;
                    *(f32x4*)(actb + la[3]) = h3;
                    *(f32x4*)(actb + la[4]) = h4;
                    *(f32x4*)(actb + la[5]) = h5;
                    if (v6) *(f32x4*)(actb + la[6]) = h6;
                }
            } else {
                const u16* pB = hB + (size_t)par_rB * HPS;
                u32 la[3]; const u16* pp[3];
                #pragma unroll
                for (int u = 0; u < 3; ++u) {
                    const int G = u * 1024 + tid;
                    const int row = G / 96, c = G - row * 96;
                    la[u] = (u32)(row * AST2 + c * 16);
                    pp[u] = pB + (size_t)row * 768 + (size_t)c * 8;
                }
                f32x4 h0, h1, h2;
                ld16x3(pp[0], pp[1], pp[2], h0, h1, h2);
                *(f32x4*)(actb + la[0]) = h0;
                *(f32x4*)(actb + la[1]) = h1;
                *(f32x4*)(actb + la[2]) = h2;
            }
            __syncthreads();   // B1: act ready

            // ---- MFMA: wave (nt, ks), rows via nl (acc0: 0-15, acc1: 16-31) ----
            f32x4 acc0 = {0.f,0.f,0.f,0.f}, acc1 = {0.f,0.f,0.f,0.f};
            if (role == 0) {
                #pragma unroll
                for (int fc = 0; fc < 8; ++fc) {
                    const int kb = (ks * 256 + fc * 32 + quad * 8) * 2;
                    bf16x8 a0 = *(const bf16x8*)(actb + nl * AST0 + kb);
                    bf16x8 a1 = *(const bf16x8*)(actb + (16 + nl) * AST0 + kb);
                    acc0 = __builtin_amdgcn_mfma_f32_16x16x32_bf16(a0, bfr[fc], acc0, 0, 0, 0);
                    acc1 = __builtin_amdgcn_mfma_f32_16x16x32_bf16(a1, bfr[fc], acc1, 0, 0, 0);
                }
            } else if (role == 1) {
                #pragma unroll
                for (int fc = 0; fc < 12; ++fc) {
                    const int kb = (ks * 384 + fc * 32 + quad * 8) * 2;
                    bf16x8 a0 = *(const bf16x8*)(actb + nl * AST1 + kb);
                    bf16x8 a1 = *(const bf16x8*)(actb + (16 + nl) * AST1 + kb);
                    acc0 = __builtin_amdgcn_mfma_f32_16x16x32_bf16(a0, bfr[fc], acc0, 0, 0, 0);
                    acc1 = __builtin_amdgcn_mfma_f32_16x16x32_bf16(a1, bfr[fc], acc1, 0, 0, 0);
                }
            } else {
                #pragma unroll
                for (int fc = 0; fc < 6; ++fc) {
                    const int kb = (ks * 192 + fc * 32 + quad * 8) * 2;
                    bf16x8 a0 = *(const bf16x8*)(actb + nl * AST2 + kb);
                    bf16x8 a1 = *(const bf16x8*)(actb + (16 + nl) * AST2 + kb);
                    acc0 = __builtin_amdgcn_mfma_f32_16x16x32_bf16(a0, bfr[fc], acc0, 0, 0, 0);
                    acc1 = __builtin_amdgcn_mfma_f32_16x16x32_bf16(a1, bfr[fc], acc1, 0, 0, 0);
                }
            }
            // D layout: col n = lane&15, row m = quad*4 + reg.
            *(f32x4*)&red[(size_t)((nt * 2 + 0) * 4 + ks) * RSLAB + nl * RCOL + quad * 4] = acc0;
            *(f32x4*)&red[(size_t)((nt * 2 + 1) * 4 + ks) * RSLAB + nl * RCOL + quad * 4] = acc1;
            __syncthreads();   // B2: red ready

            // ---- epilogue ----
            if (role == 2) {
                if (tid == 0) stu32(prog + wg * 32, (u32)(s + 1));   // hB reads done
                const int v = s - 2;
                const int orow = tid >> 5, oc2 = tid & 31;
                const int mh = orow >> 4, r16 = orow & 15;
                const int nt0 = oc2 >> 4, n0 = oc2 & 15;
                float s0 = bl0, s1 = bl1;
                #pragma unroll
                for (int k2 = 0; k2 < 4; ++k2) {
                    s0 += red[(size_t)((nt0 * 2 + mh) * 4 + k2) * RSLAB + n0 * RCOL + r16];
                    s1 += red[(size_t)(((nt0 + 2) * 2 + mh) * 4 + k2) * RSLAB + n0 * RCOL + r16];
                }
                float* o = out + ((size_t)orow * Tt + v) * OUTF + obase;
                o[oc2]      = s0;
                o[32 + oc2] = s1;
            } else if (w == 15) {
                // ---- gate wave: conflict-free f32x4 reduce + gates + h + flag ----
                const int jp = lane >> 3, rg = lane & 7;
                const int mh = rg >> 2, rr = 4 * (rg & 3);
                f32x4 pga[4], pgb[4];
                #pragma unroll
                for (int g = 0; g < 4; ++g) {
                    const int sb0 = (g * 2 + mh) * 4;
                    f32x4 sa = {0.f,0.f,0.f,0.f}, sb = {0.f,0.f,0.f,0.f};
                    #pragma unroll
                    for (int k2 = 0; k2 < 4; ++k2) {
                        sa += *(const f32x4*)&red[(size_t)(sb0 + k2) * RSLAB + (2 * jp) * RCOL + rr];
                        sb += *(const f32x4*)&red[(size_t)(sb0 + k2) * RSLAB + (2 * jp + 1) * RCOL + rr];
                    }
                    pga[g] = sa; pgb[g] = sb;
                }
                u16* dst = (role == 0) ? (hA + (size_t)par_wA * HPS)
                                       : (hB + (size_t)par_wB * HPS);
                #pragma unroll
                for (int i = 0; i < 4; ++i) {
                    const float ig0 = sigf(ba[0] + pga[0][i]);
                    const float fg0 = sigf(ba[1] + pga[1][i]);
                    const float gv0 = tanhfast(ba[2] + pga[2][i]);
                    const float og0 = sigf(ba[3] + pga[3][i]);
                    ca[i] = fg0 * ca[i] + ig0 * gv0;
                    const float h0 = og0 * tanhfast(ca[i]);
                    const float ig1 = sigf(bb[0] + pgb[0][i]);
                    const float fg1 = sigf(bb[1] + pgb[1][i]);
                    const float gv1 = tanhfast(bb[2] + pgb[2][i]);
                    const float og1 = sigf(bb[3] + pgb[3][i]);
                    cb[i] = fg1 * cb[i] + ig1 * gv1;
                    const float h1 = og1 * tanhfast(cb[i]);
                    st32ws(dst + (size_t)(4 * rg + i) * 768 + jbase + 2 * jp,
                           (u32)f2bf(h0) | ((u32)f2bf(h1) << 16));
                }
                // drain this wave's h stores, then publish progress (release)
                waitvm();
                if (lane == 0)
                    __hip_atomic_store(prog + wg * 32, (u32)(s + 1),
                                       __ATOMIC_RELEASE, __HIP_MEMORY_SCOPE_AGENT);
            }
        } // active
    } // s
}

extern "C" void kernel_launch(void* const* d_in, const int* in_sizes, int n_in,
                              void* d_out, int out_size, void* d_ws, size_t ws_size,
                              hipStream_t stream)
{
    const float* x    = (const float*)d_in[0];
    const float* Wih0 = (const float*)d_in[1];
    const float* Whh0 = (const float*)d_in[2];
    const float* bih0 = (const float*)d_in[3];
    const float* bhh0 = (const float*)d_in[4];
    const float* Wih1 = (const float*)d_in[5];
    const float* Whh1 = (const float*)d_in[6];
    const float* bih1 = (const float*)d_in[7];
    const float* bhh1 = (const float*)d_in[8];
    const float* Wlin = (const float*)d_in[9];
    const float* blin = (const float*)d_in[10];
    float* out = (float*)d_out;
    char*  ws  = (char*)d_ws;   // uses WS_BYTES = 311296 B

    static bool attr_done = false;
    if (!attr_done) {
        hipFuncSetAttribute((const void*)lstm_persist,
                            hipFuncAttributeMaxDynamicSharedMemorySize, 160 * 1024);
        attr_done = true;
    }

    hipLaunchKernelGGL(prologue, dim3(304), dim3(256), 0, stream, ws);
    hipLaunchKernelGGL(lstm_persist, dim3(NWG), dim3(NTHR), LDS_B, stream,
                       x, Wih0, Whh0, bih0, bhh0,
                       Wih1, Whh1, bih1, bhh1,
                       Wlin, blin, out, ws);
}

// Round 6
// 7998.092 us; speedup vs baseline: 1.6146x; 1.6146x over previous
//
#include <hip/hip_runtime.h>

// Problem constants
#define Tt    1024
#define INF   256
#define Hh    768
#define OUTF  128

// Grid: 48 L0 + 48 L1 + 2 LIN WGs, 1024 thr. Full batch per iteration.
// R6 = R0's proven sync protocol + R5's proven maps, with:
//  - single-pass staging (4 barriers/iter) via 133 KB dynamic LDS
//  - __launch_bounds__(1024,4): 128-VGPR budget, no scratch spills (R5 bug)
//  - x(t) prefetched before the dependency poll (independent data)
//  - role-1 poll edges merged into ONE ballot loop
#define NWG_L0  48
#define NWG_L1  48
#define NWG_LIN 2
#define NWG     (NWG_L0 + NWG_L1 + NWG_LIN)   // 98
#define NTHR    1024
#define NIT     (Tt + 2)                      // 1026

typedef unsigned int       u32;
typedef unsigned short     u16;
typedef __attribute__((ext_vector_type(8))) short bf16x8;   // 8 bf16 = 4 VGPRs
typedef __attribute__((ext_vector_type(4))) float f32x4;    // MFMA C/D

// ws layout (bytes). prog[wg]: PRIVATE 128-B line, 1 writer, pollers read.
// h rings: [3 par][32 rows][768 j] bf16 per layer.
#define PROG_OFF 0
#define HPS      24576                        // u16 per [32][768] slab
#define HA_OFF   16384
#define HB_OFF   (HA_OFF + 3 * 49152)         // 163840
#define WS_BYTES (HB_OFF + 3 * 49152)         // 311296

// LDS (dynamic). act row strides (bytes): cols*2 + 16 pad.
#define AST0   2064      // L0: 1024 cols ([x 256 | hA 768])
#define AST1   3088      // L1: 1536 cols ([hA | hB])
#define AST2   1552      // LIN: 768 cols (hB)
#define ACT0_B (32 * AST0)                    // 66048
#define ACT1_B (32 * AST1)                    // 98816
#define ACT2_B (32 * AST2)                    // 49664
#define RSLAB  272       // red slab stride (dw)  (R0-proven layout)
#define RROW   17        // red col stride (dw)
#define RED_B  (32 * RSLAB * 4)               // 34816
#define LDS_B  (ACT1_B + RED_B)               // 133632 (max over roles)

__device__ __forceinline__ float sigf(float v){ return 1.0f/(1.0f+__expf(-v)); }
__device__ __forceinline__ float tanhfast(float x){
    const float cx = fminf(fmaxf(x, -15.f), 15.f);
    const float e  = __expf(2.f * cx);
    return (e - 1.f) / (e + 1.f);
}
__device__ __forceinline__ u16 f2bf(float f){           // round-nearest-even
    u32 u = __float_as_uint(f);
    return (u16)((u + 0x7fffu + ((u>>16)&1u)) >> 16);
}
// LLC-coherent accesses for cross-WG data.
__device__ __forceinline__ void st32ws(u16* p, u32 v){
    __hip_atomic_store((u32*)p, v, __ATOMIC_RELAXED, __HIP_MEMORY_SCOPE_AGENT);
}
__device__ __forceinline__ u32 ldu32(const u32* p){
    return __hip_atomic_load(p, __ATOMIC_RELAXED, __HIP_MEMORY_SCOPE_AGENT);
}
__device__ __forceinline__ void stu32(u32* p, u32 v){
    __hip_atomic_store(p, v, __ATOMIC_RELAXED, __HIP_MEMORY_SCOPE_AGENT);
}
// Batched cache-bypassing loads: ALL loads + single vmcnt(0) drain inside ONE
// asm block (outputs never visible to regalloc before the drain — R5 lesson).
__device__ __forceinline__ void ld16x3(const u16* p0, const u16* p1, const u16* p2,
                                       f32x4& r0, f32x4& r1, f32x4& r2){
    asm volatile(
        "global_load_dwordx4 %0, %3, off sc0 sc1\n\t"
        "global_load_dwordx4 %1, %4, off sc0 sc1\n\t"
        "global_load_dwordx4 %2, %5, off sc0 sc1\n\t"
        "s_waitcnt vmcnt(0)"
        : "=&v"(r0), "=&v"(r1), "=&v"(r2)
        : "v"(p0), "v"(p1), "v"(p2)
        : "memory");
}
__device__ __forceinline__ void ld16x6(const u16* p0, const u16* p1, const u16* p2,
                                       const u16* p3, const u16* p4, const u16* p5,
                                       f32x4& r0, f32x4& r1, f32x4& r2,
                                       f32x4& r3, f32x4& r4, f32x4& r5){
    asm volatile(
        "global_load_dwordx4 %0, %6, off sc0 sc1\n\t"
        "global_load_dwordx4 %1, %7, off sc0 sc1\n\t"
        "global_load_dwordx4 %2, %8, off sc0 sc1\n\t"
        "global_load_dwordx4 %3, %9, off sc0 sc1\n\t"
        "global_load_dwordx4 %4, %10, off sc0 sc1\n\t"
        "global_load_dwordx4 %5, %11, off sc0 sc1\n\t"
        "s_waitcnt vmcnt(0)"
        : "=&v"(r0), "=&v"(r1), "=&v"(r2), "=&v"(r3), "=&v"(r4), "=&v"(r5)
        : "v"(p0), "v"(p1), "v"(p2), "v"(p3), "v"(p4), "v"(p5)
        : "memory");
}

__global__ void prologue(char* ws){
    int i = blockIdx.x * 256 + threadIdx.x;
    if (i < WS_BYTES / 4)
        __hip_atomic_store(((u32*)ws) + i, 0u, __ATOMIC_RELAXED, __HIP_MEMORY_SCOPE_AGENT);
}

__device__ __forceinline__ bf16x8 load8w(const float* p){
    float4 v0 = *(const float4*)(p);
    float4 v1 = *(const float4*)(p + 4);
    bf16x8 r;
    r[0]=(short)f2bf(v0.x); r[1]=(short)f2bf(v0.y); r[2]=(short)f2bf(v0.z); r[3]=(short)f2bf(v0.w);
    r[4]=(short)f2bf(v1.x); r[5]=(short)f2bf(v1.y); r[6]=(short)f2bf(v1.z); r[7]=(short)f2bf(v1.w);
    return r;
}

__global__ __launch_bounds__(NTHR, 4) void lstm_persist(
    const float* __restrict__ x,
    const float* __restrict__ Wih0, const float* __restrict__ Whh0,
    const float* __restrict__ bih0, const float* __restrict__ bhh0,
    const float* __restrict__ Wih1, const float* __restrict__ Whh1,
    const float* __restrict__ bih1, const float* __restrict__ bhh1,
    const float* __restrict__ Wlin, const float* __restrict__ blin,
    float* __restrict__ out, char* ws)
{
    u32* prog = (u32*)(ws + PROG_OFF);
    u16* hA   = (u16*)(ws + HA_OFF);
    u16* hB   = (u16*)(ws + HB_OFF);

    const int wg  = blockIdx.x;
    const int tid = threadIdx.x;

    extern __shared__ __align__(16) char smem[];

    const int lane = tid & 63, w = tid >> 6;
    const int quad = lane >> 4, nl = lane & 15;
    const int nt = w >> 2, ks = w & 3;          // gate/out tile, K-slice

    const int role  = (wg < NWG_L0) ? 0 : ((wg < NWG_L0 + NWG_L1) ? 1 : 2);
    const int jbase = (role == 0) ? wg * 16 : ((role == 1) ? (wg - NWG_L0) * 16 : 0);
    const int obase = (role == 2) ? (wg - NWG_L0 - NWG_L1) * 64 : 0;

    char*  actb = smem;
    float* red  = (float*)(smem + ((role == 0) ? ACT0_B : (role == 1) ? ACT1_B : ACT2_B));

    // ---- register-resident bf16 weights (B-frags): n = lane&15, k = quad*8+j ----
    // (R5-verified maps, consistent with single-pass act layout.)
    bf16x8 bfr[12];
    if (role == 0) {
        const int grow = nt * Hh + jbase + nl;
        #pragma unroll
        for (int fi = 0; fi < 8; ++fi) {
            const int ka = ks * 256 + fi * 32 + quad * 8;      // K: [x(256); hA(768)]
            const float* p = (ka < 256) ? (Wih0 + (size_t)grow * 256 + ka)
                                        : (Whh0 + (size_t)grow * 768 + (ka - 256));
            bfr[fi] = load8w(p);
        }
    } else if (role == 1) {
        const int grow = nt * Hh + jbase + nl;
        #pragma unroll
        for (int fi = 0; fi < 12; ++fi) {
            const int ka = ks * 384 + fi * 32 + quad * 8;      // K: [hA; hB]
            const float* p = (ka < 768) ? (Wih1 + (size_t)grow * 768 + ka)
                                        : (Whh1 + (size_t)grow * 768 + (ka - 768));
            bfr[fi] = load8w(p);
        }
    } else {
        const int row = obase + nt * 16 + nl;
        #pragma unroll
        for (int fi = 0; fi < 6; ++fi) {
            const int ka = ks * 192 + fi * 32 + quad * 8;
            bfr[fi] = load8w(Wlin + (size_t)row * 768 + ka);
        }
    }

    // gate threads (tid<256): (jj = tid>>5 -> j-pair {2jj,2jj+1}, b2 = tid&31 row)
    float ba0=0,ba1=0,ba2=0,ba3=0, bb0=0,bb1=0,bb2=0,bb3=0, creg0=0, creg1=0;
    float bl0 = 0.f, bl1 = 0.f;
    if (role < 2 && tid < 256) {
        const int jg0 = jbase + 2 * (tid >> 5), jg1 = jg0 + 1;
        const float* bi = (role == 0) ? bih0 : bih1;
        const float* bh = (role == 0) ? bhh0 : bhh1;
        ba0 = bi[jg0]        + bh[jg0];        bb0 = bi[jg1]        + bh[jg1];
        ba1 = bi[768 + jg0]  + bh[768 + jg0];  bb1 = bi[768 + jg1]  + bh[768 + jg1];
        ba2 = bi[1536 + jg0] + bh[1536 + jg0]; bb2 = bi[1536 + jg1] + bh[1536 + jg1];
        ba3 = bi[2304 + jg0] + bh[2304 + jg0]; bb3 = bi[2304 + jg1] + bh[2304 + jg1];
    }
    if (role == 2) {
        bl0 = blin[obase + (tid >> 5)];
        bl1 = blin[obase + 32 + (tid >> 5)];
    }

    for (int s = 0; s < NIT; ++s) {
        const int par_wA = s % 3;              // hA(s)
        const int par_rA = (s + 2) % 3;        // hA(s-1)
        const int par_wB = (s + 2) % 3;        // hB(s-1)
        const int par_rB = (s + 1) % 3;        // hB(s-2)
        const bool active = (role == 0) ? (s < Tt)
                          : (role == 1) ? (s >= 1 && s <= Tt)
                          :               (s >= 2);

        // ---- x(t) prefetch: dependency-free, in flight during the poll ----
        float4 xv0, xv1;
        const int xrow = tid >> 5, xc = tid & 31;
        if (role == 0 && active) {
            const float* xs = x + ((size_t)xrow * Tt + s) * INF + xc * 8;
            xv0 = ((const float4*)xs)[0];
            xv1 = ((const float4*)xs)[1];
        }

        // ---- dependency poll: wave 0 only, single merged ballot loop ----
        if (active && w == 0) {
            int ia = -1, ib = -1; u32 ta = 0, tb = 0;
            if (role == 0) {
                if (lane < 48) {
                    if (s >= 1) { ia = lane;      ta = (u32)s; }       // hA(s-1): L0 fin s-1
                    if (s >= 3) { ib = 48 + lane; tb = (u32)(s - 1); } // WAR: L1 fin s-2
                }
            } else if (role == 1) {
                if (lane < 48) {
                    ia = lane;      ta = (u32)s;                       // hA(s-1): L0 fin s-1
                    ib = 48 + lane; tb = (s >= 2) ? (u32)s : 0u;       // hB(s-2): L1 fin s-1
                } else if (lane < 50) {
                    ib = 48 + lane;                                    // LIN lines 96/97
                    tb = (s >= 4) ? (u32)(s - 1) : 0u;                 // WAR: LIN fin s-2
                }
            } else {
                if (lane < 48) { ia = 48 + lane; ta = (u32)s; }        // hB(s-2): L1 fin s-1
            }
            int guard = 0;
            while (guard < (1 << 24)) {
                const bool o1 = (ia < 0) || (ldu32(prog + ia * 32) >= ta);
                const bool o2 = (ib < 0) || (ldu32(prog + ib * 32) >= tb);
                if (__ballot(o1 && o2) == ~0ull) break;
                __builtin_amdgcn_s_sleep(1); ++guard;
            }
        }
        __syncthreads();   // B1

        if (active) {
            // ---- single-pass staging into full-width act ----
            if (role == 0) {
                uint4 a;
                a.x = (u32)f2bf(xv0.x) | ((u32)f2bf(xv0.y) << 16);
                a.y = (u32)f2bf(xv0.z) | ((u32)f2bf(xv0.w) << 16);
                a.z = (u32)f2bf(xv1.x) | ((u32)f2bf(xv1.y) << 16);
                a.w = (u32)f2bf(xv1.z) | ((u32)f2bf(xv1.w) << 16);
                *(uint4*)(actb + xrow * AST0 + xc * 16) = a;          // cols [0,256)
                const u16* hsrc = hA + (size_t)par_rA * HPS;
                const int r0 = tid / 96,  c0 = tid - r0 * 96;         // 3072 chunks: 3/thr
                const int G1 = 1024 + tid, r1 = G1 / 96, c1 = G1 - r1 * 96;
                const int G2 = 2048 + tid, r2 = G2 / 96, c2 = G2 - r2 * 96;
                f32x4 h0, h1, h2;
                ld16x3(hsrc + (size_t)r0 * 768 + c0 * 8,
                       hsrc + (size_t)r1 * 768 + c1 * 8,
                       hsrc + (size_t)r2 * 768 + c2 * 8, h0, h1, h2);
                *(f32x4*)(actb + r0 * AST0 + 512 + c0 * 16) = h0;     // cols [256,1024)
                *(f32x4*)(actb + r1 * AST0 + 512 + c1 * 16) = h1;
                *(f32x4*)(actb + r2 * AST0 + 512 + c2 * 16) = h2;
            } else if (role == 1) {
                const u16* pA = hA + (size_t)par_rA * HPS;
                const u16* pB = hB + (size_t)par_rB * HPS;
                const u16* pp[6]; u32 la[6];
                #pragma unroll
                for (int u = 0; u < 6; ++u) {                          // 6144 chunks: 6/thr
                    const int G = u * 1024 + tid;
                    const int row = G / 192, c = G - row * 192;
                    la[u] = (u32)(row * AST1 + c * 16);
                    pp[u] = (c < 96) ? (pA + (size_t)row * 768 + (size_t)c * 8)
                                     : (pB + (size_t)row * 768 + (size_t)(c - 96) * 8);
                }
                f32x4 h0, h1, h2, h3, h4, h5;
                ld16x6(pp[0], pp[1], pp[2], pp[3], pp[4], pp[5],
                       h0, h1, h2, h3, h4, h5);
                *(f32x4*)(actb + la[0]) = h0;
                *(f32x4*)(actb + la[1]) = h1;
                *(f32x4*)(actb + la[2]) = h2;
                *(f32x4*)(actb + la[3]) = h3;
                *(f32x4*)(actb + la[4]) = h4;
                *(f32x4*)(actb + la[5]) = h5;
            } else {
                const u16* pB = hB + (size_t)par_rB * HPS;
                const int r0 = tid / 96,  c0 = tid - r0 * 96;          // 3072 chunks: 3/thr
                const int G1 = 1024 + tid, r1 = G1 / 96, c1 = G1 - r1 * 96;
                const int G2 = 2048 + tid, r2 = G2 / 96, c2 = G2 - r2 * 96;
                f32x4 h0, h1, h2;
                ld16x3(pB + (size_t)r0 * 768 + c0 * 8,
                       pB + (size_t)r1 * 768 + c1 * 8,
                       pB + (size_t)r2 * 768 + c2 * 8, h0, h1, h2);
                *(f32x4*)(actb + r0 * AST2 + c0 * 16) = h0;
                *(f32x4*)(actb + r1 * AST2 + c1 * 16) = h1;
                *(f32x4*)(actb + r2 * AST2 + c2 * 16) = h2;
            }
            __syncthreads();   // B2: act ready

            // ---- MFMA: wave (nt, ks); acc0 rows 0-15, acc1 rows 16-31 ----
            f32x4 acc0 = {0.f,0.f,0.f,0.f}, acc1 = {0.f,0.f,0.f,0.f};
            if (role == 0) {
                #pragma unroll
                for (int fc = 0; fc < 8; ++fc) {
                    const int kb = (ks * 256 + fc * 32 + quad * 8) * 2;
                    bf16x8 a0 = *(const bf16x8*)(actb + nl * AST0 + kb);
                    bf16x8 a1 = *(const bf16x8*)(actb + (16 + nl) * AST0 + kb);
                    acc0 = __builtin_amdgcn_mfma_f32_16x16x32_bf16(a0, bfr[fc], acc0, 0, 0, 0);
                    acc1 = __builtin_amdgcn_mfma_f32_16x16x32_bf16(a1, bfr[fc], acc1, 0, 0, 0);
                }
            } else if (role == 1) {
                #pragma unroll
                for (int fc = 0; fc < 12; ++fc) {
                    const int kb = (ks * 384 + fc * 32 + quad * 8) * 2;
                    bf16x8 a0 = *(const bf16x8*)(actb + nl * AST1 + kb);
                    bf16x8 a1 = *(const bf16x8*)(actb + (16 + nl) * AST1 + kb);
                    acc0 = __builtin_amdgcn_mfma_f32_16x16x32_bf16(a0, bfr[fc], acc0, 0, 0, 0);
                    acc1 = __builtin_amdgcn_mfma_f32_16x16x32_bf16(a1, bfr[fc], acc1, 0, 0, 0);
                }
            } else {
                #pragma unroll
                for (int fc = 0; fc < 6; ++fc) {
                    const int kb = (ks * 192 + fc * 32 + quad * 8) * 2;
                    bf16x8 a0 = *(const bf16x8*)(actb + nl * AST2 + kb);
                    bf16x8 a1 = *(const bf16x8*)(actb + (16 + nl) * AST2 + kb);
                    acc0 = __builtin_amdgcn_mfma_f32_16x16x32_bf16(a0, bfr[fc], acc0, 0, 0, 0);
                    acc1 = __builtin_amdgcn_mfma_f32_16x16x32_bf16(a1, bfr[fc], acc1, 0, 0, 0);
                }
            }
            // D layout: col n = lane&15, row m = quad*4 + reg. (R0-proven red map)
            *(f32x4*)&red[(size_t)((nt * 2 + 0) * 4 + ks) * RSLAB + nl * RROW + quad * 4] = acc0;
            *(f32x4*)&red[(size_t)((nt * 2 + 1) * 4 + ks) * RSLAB + nl * RROW + quad * 4] = acc1;
            __syncthreads();   // B3: red ready

            // ---- epilogue (R0 verbatim) ----
            if (role == 2) {
                if (tid == 0) stu32(prog + wg * 32, (u32)(s + 1));   // hB reads done
                const int v = s - 2;
                const int r2o = tid >> 5, bb = tid & 31;
                const int mtr = bb >> 4, mr2 = bb & 15;
                const int nt0 = r2o >> 4, nr0 = r2o & 15;
                const int nt1 = (r2o + 32) >> 4, nr1 = (r2o + 32) & 15;
                float s0 = 0.f, s1 = 0.f;
                #pragma unroll
                for (int k2 = 0; k2 < 4; ++k2) {
                    s0 += red[(size_t)((nt0 * 2 + mtr) * 4 + k2) * RSLAB + nr0 * RROW + mr2];
                    s1 += red[(size_t)((nt1 * 2 + mtr) * 4 + k2) * RSLAB + nr1 * RROW + mr2];
                }
                float* o = out + ((size_t)bb * Tt + v) * OUTF + obase;
                o[r2o]      = s0 + bl0;
                o[32 + r2o] = s1 + bl1;
            } else if (tid < 256) {
                // ---- fused K-reduce + gates + packed h store ----
                const int jj = tid >> 5, b2 = tid & 31;
                const int mt = b2 >> 4, mr = b2 & 15;
                const int j0 = 2 * jj, j1 = 2 * jj + 1;
                float p0a=0,p1a=0,p2a=0,p3a=0, p0b=0,p1b=0,p2b=0,p3b=0;
                #pragma unroll
                for (int k2 = 0; k2 < 4; ++k2) {
                    p0a += red[(size_t)((0 * 2 + mt) * 4 + k2) * RSLAB + j0 * RROW + mr];
                    p1a += red[(size_t)((1 * 2 + mt) * 4 + k2) * RSLAB + j0 * RROW + mr];
                    p2a += red[(size_t)((2 * 2 + mt) * 4 + k2) * RSLAB + j0 * RROW + mr];
                    p3a += red[(size_t)((3 * 2 + mt) * 4 + k2) * RSLAB + j0 * RROW + mr];
                    p0b += red[(size_t)((0 * 2 + mt) * 4 + k2) * RSLAB + j1 * RROW + mr];
                    p1b += red[(size_t)((1 * 2 + mt) * 4 + k2) * RSLAB + j1 * RROW + mr];
                    p2b += red[(size_t)((2 * 2 + mt) * 4 + k2) * RSLAB + j1 * RROW + mr];
                    p3b += red[(size_t)((3 * 2 + mt) * 4 + k2) * RSLAB + j1 * RROW + mr];
                }
                const float ig0 = sigf(ba0 + p0a), fg0 = sigf(ba1 + p1a);
                const float gv0 = tanhfast(ba2 + p2a), og0 = sigf(ba3 + p3a);
                creg0 = fg0 * creg0 + ig0 * gv0;
                const float h0 = og0 * tanhfast(creg0);
                const float ig1 = sigf(bb0 + p0b), fg1 = sigf(bb1 + p1b);
                const float gv1 = tanhfast(bb2 + p2b), og1 = sigf(bb3 + p3b);
                creg1 = fg1 * creg1 + ig1 * gv1;
                const float h1 = og1 * tanhfast(creg1);
                u16* dst = (role == 0) ? (hA + (size_t)par_wA * HPS)
                                       : (hB + (size_t)par_wB * HPS);
                st32ws(dst + b2 * 768 + jbase + j0,
                       (u32)f2bf(h0) | ((u32)f2bf(h1) << 16));
            }
        }

        // ---- publish progress (barrier drains all stores first) ----
        __syncthreads();   // B_end
        if (tid == 0) stu32(prog + wg * 32, (u32)(s + 1));
    }
}

extern "C" void kernel_launch(void* const* d_in, const int* in_sizes, int n_in,
                              void* d_out, int out_size, void* d_ws, size_t ws_size,
                              hipStream_t stream)
{
    const float* x    = (const float*)d_in[0];
    const float* Wih0 = (const float*)d_in[1];
    const float* Whh0 = (const float*)d_in[2];
    const float* bih0 = (const float*)d_in[3];
    const float* bhh0 = (const float*)d_in[4];
    const float* Wih1 = (const float*)d_in[5];
    const float* Whh1 = (const float*)d_in[6];
    const float* bih1 = (const float*)d_in[7];
    const float* bhh1 = (const float*)d_in[8];
    const float* Wlin = (const float*)d_in[9];
    const float* blin = (const float*)d_in[10];
    float* out = (float*)d_out;
    char*  ws  = (char*)d_ws;   // uses WS_BYTES = 311296 B

    static bool attr_done = false;
    if (!attr_done) {
        hipFuncSetAttribute((const void*)lstm_persist,
                            hipFuncAttributeMaxDynamicSharedMemorySize, 160 * 1024);
        attr_done = true;
    }

    hipLaunchKernelGGL(prologue, dim3(304), dim3(256), 0, stream, ws);
    hipLaunchKernelGGL(lstm_persist, dim3(NWG), dim3(NTHR), LDS_B, stream,
                       x, Wih0, Whh0, bih0, bhh0,
                       Wih1, Whh1, bih1, bhh1,
                       Wlin, blin, out, ws);
}